// Round 6
// baseline (48.985 us; speedup 1.0000x reference)
//
#include <hip/hip_runtime.h>
#include <math.h>

// FNOGeoEncoder — exact algebraic reduction (only DC mode survives the mean):
//   S       = sum_t V[t,:]                          (3,)
//   X0[c]   = fc0_w[c,:].S + N*fc0_b[c]             (256,)
//   X_{k+1} = Re(sc_w[k,:,:,0])^T X_k               (4 matvecs 256x256)
//   z       = tanh((X4/N)@fc1_w^T + fc1_b)@fc2_w^T + fc2_b
//
// r5 decomposition: gather 262144 scattered lines (4096-B stride) ~30 us
// (DRAM-transaction/address-set bound), serial tail ~6 us. This version
// PIPELINES the tail under the gather: stage kernels each gather one
// chunk of W while companion blocks run the chain step whose inputs
// prior kernels completed. No device-scope sync (r4 lesson) — stream
// order only. Exposed tail: matvec3 + head.

constexpr int kN = 131072;
constexpr size_t kLayerStrideF = (size_t)256 * 256 * 512 * 2;  // 67108864 floats

// ws float offsets
constexpr size_t W_OFF   = 0;        // 4 planes of 65536: compact W[l][c][o]
constexpr size_t P_OFF   = 262144;   // vsum partials [384][3]
constexpr size_t X_OFF   = 263296;   // X0..X4 (5*256)
constexpr size_t SCR_OFF = 264576;   // warm keep-alive (256)

__device__ __forceinline__ void gather_one(const float* __restrict__ sc_w,
                                           float* __restrict__ ws,
                                           int layer, int idx) {
    ws[W_OFF + (size_t)layer * 65536 + idx] =
        sc_w[(size_t)layer * kLayerStrideF + (size_t)idx * 1024];
}

__device__ __forceinline__ void vsum_block(const float* __restrict__ V,
                                           float* __restrict__ ws,
                                           int vb, int t) {
    int q = vb * 256 + t;  // float4 index, 0..98303
    const float4 v = reinterpret_cast<const float4*>(V)[q];
    int r = q % 3;
    float a[3] = {0.f, 0.f, 0.f};
    a[r] = v.x + v.w;
    a[(r + 1) % 3] = v.y;
    a[(r + 2) % 3] = v.z;
    __shared__ float sred[3][256];
    sred[0][t] = a[0]; sred[1][t] = a[1]; sred[2][t] = a[2];
    __syncthreads();
    for (int off = 128; off > 0; off >>= 1) {
        if (t < off) {
            sred[0][t] += sred[0][t + off];
            sred[1][t] += sred[1][t + off];
            sred[2][t] += sred[2][t + off];
        }
        __syncthreads();
    }
    if (t == 0) {
        float* partials = ws + P_OFF;
        partials[vb * 3 + 0] = sred[0][0];
        partials[vb * 3 + 1] = sred[1][0];
        partials[vb * 3 + 2] = sred[2][0];
    }
}

__device__ __forceinline__ void lift_block(const float* __restrict__ fc0_w,
                                           const float* __restrict__ fc0_b,
                                           float* __restrict__ ws, int t) {
    __shared__ float red[256];
    __shared__ float S[3];
    const float* part = ws + P_OFF;
    for (int j = 0; j < 3; ++j) {
        float a = part[t * 3 + j] + ((t < 128) ? part[(t + 256) * 3 + j] : 0.f);
        red[t] = a;
        __syncthreads();
        for (int off = 128; off > 0; off >>= 1) {
            if (t < off) red[t] += red[t + off];
            __syncthreads();
        }
        if (t == 0) S[j] = red[0];
        __syncthreads();
    }
    ws[X_OFF + t] = S[0] * fc0_w[t * 3] + S[1] * fc0_w[t * 3 + 1] +
                    S[2] * fc0_w[t * 3 + 2] + (float)kN * fc0_b[t];
}

// matvec block m of 4: outputs o in [m*64, m*64+64), W[l] laid out [c][o].
__device__ __forceinline__ void matvec_block(float* __restrict__ ws,
                                             int layer, int m, int t) {
    const float* W = ws + W_OFF + (size_t)layer * 65536;
    const float* Xin = ws + X_OFF + layer * 256;
    float* Xout = ws + X_OFF + (layer + 1) * 256;
    __shared__ float xl[256];
    __shared__ float red[4][64];
    xl[t] = Xin[t];
    __syncthreads();
    int o_l = t & 63, q = t >> 6;
    int o = m * 64 + o_l;
    float acc = 0.f;
    #pragma unroll 8
    for (int i = 0; i < 64; ++i) {
        int c = q * 64 + i;
        acc += W[(size_t)c * 256 + o] * xl[c];  // 256B contiguous per wave
    }
    red[q][o_l] = acc;
    __syncthreads();
    if (t < 64) Xout[m * 64 + t] = red[0][t] + red[1][t] + red[2][t] + red[3][t];
}

__device__ __forceinline__ void warm_block(const float* __restrict__ fc1_w,
                                           const float* __restrict__ fc2_w,
                                           float* __restrict__ ws, int t) {
    const float4* f1 = (const float4*)fc1_w;  // 8192 float4
    const float4* f2 = (const float4*)fc2_w;  // 8192 float4
    float acc = 0.f;
    for (int i = t; i < 8192; i += 256) {
        float4 a = f1[i], c = f2[i];
        acc += a.x + a.y + a.z + a.w + c.x + c.y + c.z + c.w;
    }
    ws[SCR_OFF + t] = acc;  // deterministic keep-alive, never read
}

// K1: gather W0 (256 blk) + vsum (384 blk)
__global__ __launch_bounds__(256) void k1(const float* __restrict__ sc_w,
                                          const float* __restrict__ V,
                                          float* __restrict__ ws) {
    int b = blockIdx.x, t = threadIdx.x;
    if (b < 256) gather_one(sc_w, ws, 0, b * 256 + t);
    else vsum_block(V, ws, b - 256, t);
}

// K2: gather W1 (256 blk) + lift (1 blk)
__global__ __launch_bounds__(256) void k2(const float* __restrict__ sc_w,
                                          const float* __restrict__ fc0_w,
                                          const float* __restrict__ fc0_b,
                                          float* __restrict__ ws) {
    int b = blockIdx.x, t = threadIdx.x;
    if (b < 256) gather_one(sc_w, ws, 1, b * 256 + t);
    else lift_block(fc0_w, fc0_b, ws, t);
}

// K3: gather W2 first half (128 blk) + matvec0 (4 blk) + warm (1 blk)
__global__ __launch_bounds__(256) void k3(const float* __restrict__ sc_w,
                                          const float* __restrict__ fc1_w,
                                          const float* __restrict__ fc2_w,
                                          float* __restrict__ ws) {
    int b = blockIdx.x, t = threadIdx.x;
    if (b < 128) gather_one(sc_w, ws, 2, b * 256 + t);
    else if (b < 132) matvec_block(ws, 0, b - 128, t);
    else warm_block(fc1_w, fc2_w, ws, t);
}

// K4: gather W2 second half + W3 first half (256 blk) + matvec1 (4 blk)
__global__ __launch_bounds__(256) void k4(const float* __restrict__ sc_w,
                                          float* __restrict__ ws) {
    int b = blockIdx.x, t = threadIdx.x;
    if (b < 128) gather_one(sc_w, ws, 2, 32768 + b * 256 + t);
    else if (b < 256) gather_one(sc_w, ws, 3, (b - 128) * 256 + t);
    else matvec_block(ws, 1, b - 256, t);
}

// K5: gather W3 second half (128 blk) + matvec2 (4 blk)
__global__ __launch_bounds__(256) void k5(const float* __restrict__ sc_w,
                                          float* __restrict__ ws) {
    int b = blockIdx.x, t = threadIdx.x;
    if (b < 128) gather_one(sc_w, ws, 3, 32768 + b * 256 + t);
    else matvec_block(ws, 2, b - 128, t);
}

// K6: matvec3 (4 blk)
__global__ __launch_bounds__(256) void k6(float* __restrict__ ws) {
    matvec_block(ws, 3, blockIdx.x, threadIdx.x);
}

// K7: head (1 blk)
__global__ __launch_bounds__(256) void k7(const float* __restrict__ ws,
                                          const float* __restrict__ fc1_w,
                                          const float* __restrict__ fc1_b,
                                          const float* __restrict__ fc2_w,
                                          const float* __restrict__ fc2_b,
                                          float* __restrict__ out) {
    __shared__ float feat[256];
    __shared__ float hred[256];
    __shared__ float h[128];
    int t = threadIdx.x;
    feat[t] = ws[X_OFF + 4 * 256 + t] * (1.0f / (float)kN);
    __syncthreads();
    {
        int j = t & 127, s = t >> 7;  // 128 outputs, split-K by 2
        float acc = 0.f;
        #pragma unroll 8
        for (int i = 0; i < 128; ++i)
            acc += feat[s * 128 + i] * fc1_w[j * 256 + s * 128 + i];
        hred[s * 128 + j] = acc;
        __syncthreads();
        if (t < 128) h[t] = tanhf(hred[t] + hred[128 + t] + fc1_b[t]);
        __syncthreads();
    }
    float acc = fc2_b[t];
    #pragma unroll 8
    for (int i = 0; i < 128; ++i) acc += h[i] * fc2_w[t * 128 + i];
    out[t] = acc;
}

extern "C" void kernel_launch(void* const* d_in, const int* in_sizes, int n_in,
                              void* d_out, int out_size, void* d_ws, size_t ws_size,
                              hipStream_t stream) {
    const float* V     = (const float*)d_in[0];
    const float* fc0_w = (const float*)d_in[1];
    const float* fc0_b = (const float*)d_in[2];
    const float* sc_w  = (const float*)d_in[3];
    const float* fc1_w = (const float*)d_in[4];
    const float* fc1_b = (const float*)d_in[5];
    const float* fc2_w = (const float*)d_in[6];
    const float* fc2_b = (const float*)d_in[7];
    float* out = (float*)d_out;
    float* ws = (float*)d_ws;

    k1<<<640, 256, 0, stream>>>(sc_w, V, ws);
    k2<<<257, 256, 0, stream>>>(sc_w, fc0_w, fc0_b, ws);
    k3<<<133, 256, 0, stream>>>(sc_w, fc1_w, fc2_w, ws);
    k4<<<260, 256, 0, stream>>>(sc_w, ws);
    k5<<<132, 256, 0, stream>>>(sc_w, ws);
    k6<<<4, 256, 0, stream>>>(ws);
    k7<<<1, 256, 0, stream>>>(ws, fc1_w, fc1_b, fc2_w, fc2_b, out);
}

// Round 7
// 36.804 us; speedup vs baseline: 1.3310x; 1.3310x over previous
//
#include <hip/hip_runtime.h>
#include <math.h>

// FNOGeoEncoder — exact algebraic reduction (only DC mode survives the mean):
//   S       = sum_t V[t,:]                          (3,)
//   X0[c]   = fc0_w[c,:].S + N*fc0_b[c]             (256,)
//   X_{k+1} = Re(sc_w[k,:,:,0])^T X_k               (4 matvecs 256x256)
//   feat    = X4 / N
//   z       = tanh(feat@fc1_w^T + fc1_b)@fc2_w^T + fc2_b
//
// CHAMPION (r2 structure, 36.8 us). Cost decomposition, all measured:
//  - gather: 262144 mandatory lines at 4096-B-aligned stride ~30 us.
//    DRAM-transaction/address-set bound. Invariant across issue orders
//    (r1/r2/r3); splitting into stages loses queue occupancy (r6: +12us);
//    must be ONE kernel with max outstanding requests.
//  - tail: ~6 us, conserved across {1-block, multi-launch, fused} —
//    serial 4-layer dependency x cross-CU visibility floor.
//  - device-scope barriers/atomic fan-in: ~20 us each (r4). Never.

constexpr int kN = 131072;
constexpr int kWidth = 256;
constexpr int kModes = 512;
constexpr int kLayers = 4;
constexpr size_t kLayerStride = (size_t)kWidth * kWidth * kModes * 2;  // floats
constexpr int kGatherBlocks = 256;   // 256 blk * 256 thr * 4 layers = 262144 gathers
constexpr int kVsumBlocks = 384;     // 384 blk * 256 thr * 1 float4 = 98304 = 131072*3/4

// ws layout (floats):
//   [0, 262144)            compact W[l][c][o]
//   [262144, 262144+1152)  vsum partials [384][3]

__global__ __launch_bounds__(256) void stageA(const float* __restrict__ sc_w,
                                              const float* __restrict__ V,
                                              float* __restrict__ ws) {
    int b = blockIdx.x, t = threadIdx.x;
    if (b < kGatherBlocks) {
        int rem = b * 256 + t;  // flat (c,o), 0..65535; consecutive t -> consecutive o
        const float* src = sc_w + (size_t)rem * (size_t)(kModes * 2);
        #pragma unroll
        for (int l = 0; l < kLayers; ++l) {
            ws[(size_t)l * 65536 + rem] = src[(size_t)l * kLayerStride];
        }
    } else {
        int vb = b - kGatherBlocks;
        int q = vb * 256 + t;  // float4 index, 0..98303
        const float4 v = reinterpret_cast<const float4*>(V)[q];
        int r = q % 3;         // component of first element (f=4q, f%3 == q%3)
        float a[3] = {0.f, 0.f, 0.f};
        a[r] = v.x + v.w;
        a[(r + 1) % 3] = v.y;
        a[(r + 2) % 3] = v.z;
        __shared__ float sred[3][256];
        sred[0][t] = a[0]; sred[1][t] = a[1]; sred[2][t] = a[2];
        __syncthreads();
        for (int off = 128; off > 0; off >>= 1) {
            if (t < off) {
                sred[0][t] += sred[0][t + off];
                sred[1][t] += sred[1][t + off];
                sred[2][t] += sred[2][t + off];
            }
            __syncthreads();
        }
        if (t == 0) {
            float* partials = ws + 262144;
            partials[vb * 3 + 0] = sred[0][0];
            partials[vb * 3 + 1] = sred[1][0];
            partials[vb * 3 + 2] = sred[2][0];
        }
    }
}

__global__ __launch_bounds__(1024) void stageB(const float* __restrict__ ws,
                                               const float* __restrict__ fc0_w,
                                               const float* __restrict__ fc0_b,
                                               const float* __restrict__ fc1_w,
                                               const float* __restrict__ fc1_b,
                                               const float* __restrict__ fc2_w,
                                               const float* __restrict__ fc2_b,
                                               float* __restrict__ out) {
    __shared__ float red[1024];
    __shared__ float xbuf[256];
    __shared__ float part[4][256];
    __shared__ float S[3];
    __shared__ float hbuf[128];
    int t = threadIdx.x;
    const float* partials = ws + 262144;

    // S[j] = fixed-order tree sum of partials[384][j]
    for (int j = 0; j < 3; ++j) {
        red[t] = (t < kVsumBlocks) ? partials[t * 3 + j] : 0.f;
        __syncthreads();
        for (int off = 512; off > 0; off >>= 1) {
            if (t < off) red[t] += red[t + off];
            __syncthreads();
        }
        if (t == 0) S[j] = red[0];
        __syncthreads();
    }

    // lift at DC
    if (t < 256) {
        xbuf[t] = S[0] * fc0_w[t * 3] + S[1] * fc0_w[t * 3 + 1] +
                  S[2] * fc0_w[t * 3 + 2] + (float)kN * fc0_b[t];
    }
    __syncthreads();

    // 4 spectral-DC matvecs, split-K by 4 wave-groups
    int g = t >> 8, o = t & 255;
    for (int l = 0; l < kLayers; ++l) {
        const float* W = ws + (size_t)l * 65536;
        float acc = 0.f;
        int c0 = g * 64;
        #pragma unroll 8
        for (int i = 0; i < 64; ++i) {
            int c = c0 + i;
            acc += W[c * 256 + o] * xbuf[c];  // coalesced across o per iteration
        }
        part[g][o] = acc;
        __syncthreads();
        if (t < 256) xbuf[t] = part[0][t] + part[1][t] + part[2][t] + part[3][t];
        __syncthreads();
    }

    // feat = X4 / N
    if (t < 256) xbuf[t] *= (1.0f / (float)kN);
    __syncthreads();

    // fc1 + tanh: 128 outputs, split-K by 8
    {
        int j = t & 127, s = t >> 7;
        float acc = 0.f;
        int c0 = s * 32;
        #pragma unroll 8
        for (int i = 0; i < 32; ++i) acc += xbuf[c0 + i] * fc1_w[j * 256 + c0 + i];
        red[s * 128 + j] = acc;
        __syncthreads();
        if (t < 128) {
            float a = 0.f;
            #pragma unroll
            for (int s2 = 0; s2 < 8; ++s2) a += red[s2 * 128 + t];
            hbuf[t] = tanhf(a + fc1_b[t]);
        }
        __syncthreads();
    }

    // fc2: 256 outputs, split-K by 4
    {
        int k = t & 255, s = t >> 8;
        float acc = 0.f;
        int c0 = s * 32;
        #pragma unroll 8
        for (int i = 0; i < 32; ++i) acc += hbuf[c0 + i] * fc2_w[k * 128 + c0 + i];
        red[s * 256 + k] = acc;
        __syncthreads();
        if (t < 256) out[t] = red[t] + red[256 + t] + red[512 + t] + red[768 + t] + fc2_b[t];
    }
}

extern "C" void kernel_launch(void* const* d_in, const int* in_sizes, int n_in,
                              void* d_out, int out_size, void* d_ws, size_t ws_size,
                              hipStream_t stream) {
    const float* V     = (const float*)d_in[0];
    const float* fc0_w = (const float*)d_in[1];
    const float* fc0_b = (const float*)d_in[2];
    const float* sc_w  = (const float*)d_in[3];
    const float* fc1_w = (const float*)d_in[4];
    const float* fc1_b = (const float*)d_in[5];
    const float* fc2_w = (const float*)d_in[6];
    const float* fc2_b = (const float*)d_in[7];
    float* out = (float*)d_out;
    float* ws = (float*)d_ws;

    stageA<<<kGatherBlocks + kVsumBlocks, 256, 0, stream>>>(sc_w, V, ws);
    stageB<<<1, 1024, 0, stream>>>(ws, fc0_w, fc0_b, fc1_w, fc1_b, fc2_w, fc2_b, out);
}